// Round 6
// baseline (120.890 us; speedup 1.0000x reference)
//
#include <hip/hip_runtime.h>

#define B 16
#define ENC_T 512
#define ENC_DIM 512
#define DEC_T 2048
#define ROWS 16                      // decoder rows per block
#define NBLK (B * DEC_T / ROWS)      // 2048 blocks

// R4's fused kernel, verbatim (fastest so far). Launched 3x to separate
// fixed per-replay overhead c from kernel time k: dur = c + 3k, R4: c + k = 44.
__global__ __launch_bounds__(512) void fused_kernel(const float* __restrict__ enc,
                                                    const float* __restrict__ enc_len,
                                                    float* __restrict__ out,
                                                    float* __restrict__ att) {
    __shared__ int si[ENC_T];        // inclusive cumsum (= end[e])
    __shared__ int wsum[8];
    __shared__ int sseg[ROWS];

    const int tid = threadIdx.x;     // 0..511
    const int bt0 = blockIdx.x * ROWS;   // global row index of first row
    const int b   = bt0 >> 11;           // / DEC_T

    // ---- phase 1: cumsum of batch b durations (wave shfl scan, 8 waves) ----
    int v = (int)enc_len[(size_t)b * ENC_T + tid];   // small ints, exact
    const int lane = tid & 63;
    #pragma unroll
    for (int off = 1; off < 64; off <<= 1) {
        int u = __shfl_up(v, off, 64);
        if (lane >= off) v += u;
    }
    const int w = tid >> 6;
    if (lane == 63) wsum[w] = v;
    __syncthreads();
    int woff = 0;
    for (int k = 0; k < w; ++k) woff += wsum[k];     // <=7 broadcast LDS reads
    si[tid] = v + woff;
    __syncthreads();

    // ---- phase 2: segment id for each of this block's ROWS rows ----
    if (tid < ROWS) {
        const int t = (bt0 - (b << 11)) + tid;       // t within batch
        int lo = 0, hi = ENC_T;
        while (lo < hi) {                            // upper_bound: first si[e] > t
            int mid = (lo + hi) >> 1;
            if (si[mid] > t) hi = mid; else lo = mid + 1;
        }
        sseg[tid] = (lo < ENC_T) ? lo : -1;
    }
    __syncthreads();

    // ---- phase 3: stream the rows. groups 0,1 -> out; groups 2,3 -> att ----
    const int g = tid >> 7;          // 0..3 (two waves per group)
    const int j = tid & 127;
    if (g < 2) {
        #pragma unroll
        for (int r8 = 0; r8 < ROWS / 2; ++r8) {
            const int r = (r8 << 1) | g;
            const int s = sseg[r];
            float4 o = make_float4(0.f, 0.f, 0.f, 0.f);
            if (s >= 0)
                o = ((const float4*)(enc + ((size_t)b * ENC_T + s) * ENC_DIM))[j];
            ((float4*)(out + (size_t)(bt0 + r) * ENC_DIM))[j] = o;
        }
    } else {
        const int e0 = j << 2;
        #pragma unroll
        for (int r8 = 0; r8 < ROWS / 2; ++r8) {
            const int r = (r8 << 1) | (g - 2);
            const int s = sseg[r];
            float4 a = make_float4(0.f, 0.f, 0.f, 0.f);
            if (s >= e0 && s < e0 + 4) ((float*)&a)[s - e0] = 1.0f;
            ((float4*)(att + (size_t)(bt0 + r) * ENC_T))[j] = a;
        }
    }
}

extern "C" void kernel_launch(void* const* d_in, const int* in_sizes, int n_in,
                              void* d_out, int out_size, void* d_ws, size_t ws_size,
                              hipStream_t stream) {
    const float* enc     = (const float*)d_in[0];   // [B, ENC_T, ENC_DIM]
    const float* enc_len = (const float*)d_in[2];   // [B, ENC_T]

    float* out = (float*)d_out;                          // [B, DEC_T, ENC_DIM]
    float* att = out + (size_t)B * DEC_T * ENC_DIM;      // [B, DEC_T, ENC_T]

    // Idempotent: launched 3x on purpose (overhead-vs-kernel-time measurement).
    hipLaunchKernelGGL(fused_kernel, dim3(NBLK), dim3(512), 0, stream,
                       enc, enc_len, out, att);
    hipLaunchKernelGGL(fused_kernel, dim3(NBLK), dim3(512), 0, stream,
                       enc, enc_len, out, att);
    hipLaunchKernelGGL(fused_kernel, dim3(NBLK), dim3(512), 0, stream,
                       enc, enc_len, out, att);
}

// Round 7
// 91.803 us; speedup vs baseline: 1.3169x; 1.3169x over previous
//
#include <hip/hip_runtime.h>

#define B 16
#define ENC_T 512
#define ENC_DIM 512
#define DEC_T 2048
#define ROWS 16                      // decoder rows per block
#define NBLK (B * DEC_T / ROWS)      // 2048 blocks
#define REPS 4                       // measurement: repeat stream phase to surface counters

// R4 fused kernel with phase-3 repeated REPS times (idempotent) so our dispatch
// outranks the harness's 75us fill kernels in the rocprof table and we finally
// see FETCH_SIZE / WRITE_SIZE / VALUBusy / Occupancy for OUR code.
__global__ __launch_bounds__(512) void fused_kernel(const float* __restrict__ enc,
                                                    const float* __restrict__ enc_len,
                                                    float* __restrict__ out,
                                                    float* __restrict__ att) {
    __shared__ int si[ENC_T];        // inclusive cumsum (= end[e])
    __shared__ int wsum[8];
    __shared__ int sseg[ROWS];

    const int tid = threadIdx.x;     // 0..511
    const int bt0 = blockIdx.x * ROWS;   // global row index of first row
    const int b   = bt0 >> 11;           // / DEC_T

    // ---- phase 1: cumsum of batch b durations (wave shfl scan, 8 waves) ----
    int v = (int)enc_len[(size_t)b * ENC_T + tid];   // small ints, exact
    const int lane = tid & 63;
    #pragma unroll
    for (int off = 1; off < 64; off <<= 1) {
        int u = __shfl_up(v, off, 64);
        if (lane >= off) v += u;
    }
    const int w = tid >> 6;
    if (lane == 63) wsum[w] = v;
    __syncthreads();
    int woff = 0;
    for (int k = 0; k < w; ++k) woff += wsum[k];     // <=7 broadcast LDS reads
    si[tid] = v + woff;
    __syncthreads();

    // ---- phase 2: segment id for each of this block's ROWS rows ----
    if (tid < ROWS) {
        const int t = (bt0 - (b << 11)) + tid;       // t within batch
        int lo = 0, hi = ENC_T;
        while (lo < hi) {                            // upper_bound: first si[e] > t
            int mid = (lo + hi) >> 1;
            if (si[mid] > t) hi = mid; else lo = mid + 1;
        }
        sseg[tid] = (lo < ENC_T) ? lo : -1;
    }
    __syncthreads();

    // ---- phase 3 (x REPS): stream the rows ----
    const int g = tid >> 7;          // 0..3 (two waves per group)
    const int j = tid & 127;
    for (int rep = 0; rep < REPS; ++rep) {
        if (g < 2) {
            #pragma unroll
            for (int r8 = 0; r8 < ROWS / 2; ++r8) {
                const int r = (r8 << 1) | g;
                const int s = sseg[r];
                float4 o = make_float4(0.f, 0.f, 0.f, 0.f);
                if (s >= 0)
                    o = ((const float4*)(enc + ((size_t)b * ENC_T + s) * ENC_DIM))[j];
                ((float4*)(out + (size_t)(bt0 + r) * ENC_DIM))[j] = o;
            }
        } else {
            const int e0 = j << 2;
            #pragma unroll
            for (int r8 = 0; r8 < ROWS / 2; ++r8) {
                const int r = (r8 << 1) | (g - 2);
                const int s = sseg[r];
                float4 a = make_float4(0.f, 0.f, 0.f, 0.f);
                if (s >= e0 && s < e0 + 4) ((float*)&a)[s - e0] = 1.0f;
                ((float4*)(att + (size_t)(bt0 + r) * ENC_T))[j] = a;
            }
        }
        asm volatile("" ::: "memory");   // keep each rep's loads+stores live
    }
}

extern "C" void kernel_launch(void* const* d_in, const int* in_sizes, int n_in,
                              void* d_out, int out_size, void* d_ws, size_t ws_size,
                              hipStream_t stream) {
    const float* enc     = (const float*)d_in[0];   // [B, ENC_T, ENC_DIM]
    const float* enc_len = (const float*)d_in[2];   // [B, ENC_T]

    float* out = (float*)d_out;                          // [B, DEC_T, ENC_DIM]
    float* att = out + (size_t)B * DEC_T * ENC_DIM;      // [B, DEC_T, ENC_T]

    hipLaunchKernelGGL(fused_kernel, dim3(NBLK), dim3(512), 0, stream,
                       enc, enc_len, out, att);
}

// Round 8
// 30.873 us; speedup vs baseline: 3.9157x; 2.9735x over previous
//
#include <hip/hip_runtime.h>

#define B 16
#define ENC_T 512
#define ENC_DIM 512
#define DEC_T 2048
#define ROWS 32                      // decoder rows per block
#define NBLK (B * DEC_T / ROWS)      // 1024 blocks

// att is zeroed by hipMemsetAsync (fillBufferAligned path, measured 6.9-7.2 TB/s).
// This kernel writes only the `out` gather stream + scatters the 32768 ones into att.
__global__ __launch_bounds__(512) void out_writer(const float* __restrict__ enc,
                                                  const float* __restrict__ enc_len,
                                                  float* __restrict__ out,
                                                  float* __restrict__ att) {
    __shared__ int   si[ENC_T];      // inclusive cumsum (= end[e])
    __shared__ int   wsum[8];
    __shared__ short sseg[ROWS];

    const int tid = threadIdx.x;     // 0..511
    const int bt0 = blockIdx.x * ROWS;   // first global row of this block
    const int b   = bt0 >> 11;           // / DEC_T (blocks never straddle batches)

    // ---- phase 1: cumsum of batch b durations (wave shfl scan, 8 waves) ----
    int v = (int)enc_len[(size_t)b * ENC_T + tid];   // small ints, exact in f32
    const int lane = tid & 63;
    #pragma unroll
    for (int off = 1; off < 64; off <<= 1) {
        int u = __shfl_up(v, off, 64);
        if (lane >= off) v += u;
    }
    const int w = tid >> 6;
    if (lane == 63) wsum[w] = v;
    __syncthreads();
    int woff = 0;
    for (int k = 0; k < w; ++k) woff += wsum[k];     // <=7 broadcast LDS reads
    si[tid] = v + woff;
    __syncthreads();

    // ---- phase 2: segment ids + att scatter (memset already zeroed att) ----
    if (tid < ROWS) {
        const int t = (bt0 & (DEC_T - 1)) + tid;     // t within batch
        int lo = 0, hi = ENC_T;
        while (lo < hi) {                            // upper_bound: first si[e] > t
            int mid = (lo + hi) >> 1;
            if (si[mid] > t) hi = mid; else lo = mid + 1;
        }
        const int s = (lo < ENC_T) ? lo : -1;
        sseg[tid] = (short)s;
        if (s >= 0) att[(size_t)(bt0 + tid) * ENC_T + s] = 1.0f;  // one dirty line/row
    }
    __syncthreads();

    // ---- phase 3: stream out rows, 4 rows per iteration (8 KB contiguous) ----
    const int r = tid >> 7;          // 0..3
    const int j = tid & 127;         // float4 index within row
    const float4* encb = (const float4*)(enc + (size_t)b * ENC_T * ENC_DIM);
    float4* ob = (float4*)(out + (size_t)bt0 * ENC_DIM);
    #pragma unroll
    for (int rr = 0; rr < ROWS; rr += 4) {
        const int row = rr + r;
        const int s = sseg[row];
        float4 o = make_float4(0.f, 0.f, 0.f, 0.f);
        if (s >= 0) o = encb[s * 128 + j];
        ob[row * 128 + j] = o;
    }
}

extern "C" void kernel_launch(void* const* d_in, const int* in_sizes, int n_in,
                              void* d_out, int out_size, void* d_ws, size_t ws_size,
                              hipStream_t stream) {
    const float* enc     = (const float*)d_in[0];   // [B, ENC_T, ENC_DIM]
    const float* enc_len = (const float*)d_in[2];   // [B, ENC_T]

    float* out = (float*)d_out;                          // [B, DEC_T, ENC_DIM]
    float* att = out + (size_t)B * DEC_T * ENC_DIM;      // [B, DEC_T, ENC_T]

    const size_t att_bytes = (size_t)B * DEC_T * ENC_T * sizeof(float);  // 64 MB
    hipMemsetAsync(att, 0, att_bytes, stream);           // fast fill path for the zeros

    hipLaunchKernelGGL(out_writer, dim3(NBLK), dim3(512), 0, stream,
                       enc, enc_len, out, att);
}